// Round 3
// baseline (297.663 us; speedup 1.0000x reference)
//
#include <hip/hip_runtime.h>

#define LOG2E 1.4426950408889634f

typedef __attribute__((ext_vector_type(4))) float  f32x4;
typedef __attribute__((ext_vector_type(8))) __bf16 bf16x8;   // MFMA A/B fragment
typedef __attribute__((ext_vector_type(8))) short  sh8;      // 16B bf16-bits copy
typedef __attribute__((ext_vector_type(4))) short  sh4;

__device__ __forceinline__ short f2bf(float f) {
  union { float f; unsigned u; } x; x.f = f;
  unsigned r = (x.u + 0x7fffu + ((x.u >> 16) & 1u)) >> 16;  // RNE
  return (short)r;
}

// ---------- weight transpose + convert: WT[n][k] = bf16(W[k][n]), 512x512 ----------
__global__ __launch_bounds__(256)
void wtrans(const float* __restrict__ Wq, const float* __restrict__ Wk,
            const float* __restrict__ Wv, const float* __restrict__ Wo,
            short* __restrict__ WqT, short* __restrict__ WkT,
            short* __restrict__ WvT, short* __restrict__ WoT)
{
  const float* W; short* WT;
  switch (blockIdx.z) {
    case 0:  W = Wq; WT = WqT; break;
    case 1:  W = Wk; WT = WkT; break;
    case 2:  W = Wv; WT = WvT; break;
    default: W = Wo; WT = WoT; break;
  }
  __shared__ float ts[32][33];
  const int t = threadIdx.x;
  const int k0 = blockIdx.x * 32, n0 = blockIdx.y * 32;
  const int r = t >> 3, c4 = (t & 7) * 4;
  float4 v = *(const float4*)&W[(size_t)(k0 + r) * 512 + n0 + c4];
  ts[r][c4 + 0] = v.x; ts[r][c4 + 1] = v.y; ts[r][c4 + 2] = v.z; ts[r][c4 + 3] = v.w;
  __syncthreads();
  sh4 o;
  o[0] = f2bf(ts[c4 + 0][r]); o[1] = f2bf(ts[c4 + 1][r]);
  o[2] = f2bf(ts[c4 + 2][r]); o[3] = f2bf(ts[c4 + 3][r]);
  *(sh4*)&WT[(size_t)(n0 + r) * 512 + k0 + c4] = o;
}

// ---------- generic 128x128-tile GEMM, K=512, C = A @ B^T (+bias) ----------
// A_F32/B_F32: operand is fp32 (converted to bf16 during staging), else bf16 bits.
// OMODE 0: out bf16, head-split [B,H,S,64] from C[R in 8192][C in 512]
// OMODE 1: out bf16, V^T layout [B,H,64,S] from C[m=dcol in 512][n=srow in 8192]
// OMODE 2: out fp32 plain [M][512]
template<bool A_F32, bool B_F32, int OMODE>
__global__ __launch_bounds__(256)
void gemm512(const void* __restrict__ Ap, const void* __restrict__ Bp,
             const float* __restrict__ bias, void* __restrict__ outp)
{
  __shared__ short As[128][72];   // +8 pad: row stride 144B -> 2-way bank alias (free)
  __shared__ short Bs[128][72];
  const int rm = blockIdx.x * 128, cn = blockIdx.y * 128;
  const int tid = threadIdx.x, l = tid & 63, wid = tid >> 6;
  const int wr = wid >> 1, wc = wid & 1;
  const int lr = l & 15, lk = (l >> 4) * 8, lj = (l >> 4) * 4;
  const int sr = tid >> 1, sc = (tid & 1) * 32;

  f32x4 acc[4][4];
  const f32x4 z4 = {0.f, 0.f, 0.f, 0.f};
  #pragma unroll
  for (int i = 0; i < 4; ++i)
    #pragma unroll
    for (int j = 0; j < 4; ++j) acc[i][j] = z4;

  for (int k0 = 0; k0 < 512; k0 += 64) {
    if constexpr (A_F32) {
      const float* A = (const float*)Ap + (size_t)(rm + sr) * 512 + k0 + sc;
      #pragma unroll
      for (int g = 0; g < 4; ++g) {
        float4 f0 = ((const float4*)A)[2 * g];
        float4 f1 = ((const float4*)A)[2 * g + 1];
        sh8 s;
        s[0] = f2bf(f0.x); s[1] = f2bf(f0.y); s[2] = f2bf(f0.z); s[3] = f2bf(f0.w);
        s[4] = f2bf(f1.x); s[5] = f2bf(f1.y); s[6] = f2bf(f1.z); s[7] = f2bf(f1.w);
        *(sh8*)&As[sr][sc + 8 * g] = s;
      }
    } else {
      const short* A = (const short*)Ap + (size_t)(rm + sr) * 512 + k0 + sc;
      #pragma unroll
      for (int g = 0; g < 4; ++g)
        *(sh8*)&As[sr][sc + 8 * g] = ((const sh8*)A)[g];
    }
    if constexpr (B_F32) {
      const float* B = (const float*)Bp + (size_t)(cn + sr) * 512 + k0 + sc;
      #pragma unroll
      for (int g = 0; g < 4; ++g) {
        float4 f0 = ((const float4*)B)[2 * g];
        float4 f1 = ((const float4*)B)[2 * g + 1];
        sh8 s;
        s[0] = f2bf(f0.x); s[1] = f2bf(f0.y); s[2] = f2bf(f0.z); s[3] = f2bf(f0.w);
        s[4] = f2bf(f1.x); s[5] = f2bf(f1.y); s[6] = f2bf(f1.z); s[7] = f2bf(f1.w);
        *(sh8*)&Bs[sr][sc + 8 * g] = s;
      }
    } else {
      const short* B = (const short*)Bp + (size_t)(cn + sr) * 512 + k0 + sc;
      #pragma unroll
      for (int g = 0; g < 4; ++g)
        *(sh8*)&Bs[sr][sc + 8 * g] = ((const sh8*)B)[g];
    }
    __syncthreads();
    #pragma unroll
    for (int kk = 0; kk < 2; ++kk) {
      bf16x8 af[4], bfr[4];
      #pragma unroll
      for (int mi = 0; mi < 4; ++mi)
        af[mi] = *(const bf16x8*)&As[wr * 64 + mi * 16 + lr][kk * 32 + lk];
      #pragma unroll
      for (int ni = 0; ni < 4; ++ni)
        bfr[ni] = *(const bf16x8*)&Bs[wc * 64 + ni * 16 + lr][kk * 32 + lk];
      #pragma unroll
      for (int mi = 0; mi < 4; ++mi)
        #pragma unroll
        for (int ni = 0; ni < 4; ++ni)
          acc[mi][ni] = __builtin_amdgcn_mfma_f32_16x16x32_bf16(af[mi], bfr[ni], acc[mi][ni], 0, 0, 0);
    }
    __syncthreads();
  }

  #pragma unroll
  for (int mi = 0; mi < 4; ++mi) {
    #pragma unroll
    for (int ni = 0; ni < 4; ++ni) {
      const int row = rm + wr * 64 + mi * 16 + lj;
      const int col = cn + wc * 64 + ni * 16 + lr;
      if constexpr (OMODE == 2) {
        float* out = (float*)outp;
        const float bv = bias[col];
        #pragma unroll
        for (int j = 0; j < 4; ++j)
          out[(size_t)(row + j) * 512 + col] = acc[mi][ni][j] + bv;
      } else if constexpr (OMODE == 0) {
        short* out = (short*)outp;
        const float bv = bias[col];
        const int h = col >> 6, d = col & 63;
        #pragma unroll
        for (int j = 0; j < 4; ++j) {
          const int R = row + j, b = R >> 11, s = R & 2047;
          out[(((size_t)(b * 8 + h)) * 2048 + s) * 64 + d] = f2bf(acc[mi][ni][j] + bv);
        }
      } else {  // OMODE == 1: V^T
        short* out = (short*)outp;
        const int b = col >> 11, s = col & 2047;
        #pragma unroll
        for (int j = 0; j < 4; ++j) {
          const int mr = row + j;
          const int h = mr >> 6, d = mr & 63;
          out[(((size_t)(b * 8 + h)) * 64 + d) * 2048 + s] = f2bf(acc[mi][ni][j] + bias[mr]);
        }
      }
    }
  }
}

// ---------- flash attention: 4 waves x 32 q-rows, KV tile = 64 ----------
__global__ __launch_bounds__(256)
void attn(const short* __restrict__ Qh, const short* __restrict__ Kh,
          const short* __restrict__ VhT, short* __restrict__ Cc)
{
  __shared__ short Ks[64][72];        // K tile  [kpos][d], padded
  __shared__ short Vs[64][72];        // V^T tile [d][kpos], padded
  __shared__ short Ps[4][32][72];     // per-wave P tile [qrow][kpos], padded

  const int qt = blockIdx.x, bh = blockIdx.y;
  const int tid = threadIdx.x, l = tid & 63, w = tid >> 6;
  const int lr = l & 15, lk = (l >> 4) * 8, lj = (l >> 4) * 4;
  const int q0 = qt * 128 + w * 32;

  const short* Qb = Qh + (size_t)bh * 2048 * 64;
  const short* Kb = Kh + (size_t)bh * 2048 * 64;
  const short* Vb = VhT + (size_t)bh * 64 * 2048;

  bf16x8 aq[2][2];
  #pragma unroll
  for (int mi = 0; mi < 2; ++mi)
    #pragma unroll
    for (int kk = 0; kk < 2; ++kk)
      aq[mi][kk] = *(const bf16x8*)&Qb[(size_t)(q0 + mi * 16 + lr) * 64 + kk * 32 + lk];

  const f32x4 z4 = {0.f, 0.f, 0.f, 0.f};
  f32x4 accO[2][4];
  float mrun[2][4], lrun[2][4];
  #pragma unroll
  for (int mi = 0; mi < 2; ++mi) {
    #pragma unroll
    for (int ni = 0; ni < 4; ++ni) accO[mi][ni] = z4;
    #pragma unroll
    for (int j = 0; j < 4; ++j) { mrun[mi][j] = -1e30f; lrun[mi][j] = 0.f; }
  }

  const int str = tid >> 2, stc = (tid & 3) * 16;

  for (int kv = 0; kv < 2048; kv += 64) {
    {
      const sh8* ksrc = (const sh8*)&Kb[(size_t)(kv + str) * 64 + stc];
      *(sh8*)&Ks[str][stc]     = ksrc[0];
      *(sh8*)&Ks[str][stc + 8] = ksrc[1];
      const sh8* vsrc = (const sh8*)&Vb[(size_t)str * 2048 + kv + stc];
      *(sh8*)&Vs[str][stc]     = vsrc[0];
      *(sh8*)&Vs[str][stc + 8] = vsrc[1];
    }
    __syncthreads();

    // S = Q K^T
    f32x4 accS[2][4];
    #pragma unroll
    for (int mi = 0; mi < 2; ++mi)
      #pragma unroll
      for (int ni = 0; ni < 4; ++ni) accS[mi][ni] = z4;
    #pragma unroll
    for (int kk = 0; kk < 2; ++kk) {
      bf16x8 bk[4];
      #pragma unroll
      for (int ni = 0; ni < 4; ++ni)
        bk[ni] = *(const bf16x8*)&Ks[ni * 16 + lr][kk * 32 + lk];
      #pragma unroll
      for (int mi = 0; mi < 2; ++mi)
        #pragma unroll
        for (int ni = 0; ni < 4; ++ni)
          accS[mi][ni] = __builtin_amdgcn_mfma_f32_16x16x32_bf16(aq[mi][kk], bk[ni], accS[mi][ni], 0, 0, 0);
    }

    // online softmax (row = q). Row-reduce across the 16 lanes of the group.
    #pragma unroll
    for (int mi = 0; mi < 2; ++mi) {
      #pragma unroll
      for (int j = 0; j < 4; ++j) {
        float s0 = accS[mi][0][j] * 0.125f, s1 = accS[mi][1][j] * 0.125f;
        float s2 = accS[mi][2][j] * 0.125f, s3 = accS[mi][3][j] * 0.125f;
        float mx = fmaxf(fmaxf(s0, s1), fmaxf(s2, s3));
        mx = fmaxf(mx, __shfl_xor(mx, 1));
        mx = fmaxf(mx, __shfl_xor(mx, 2));
        mx = fmaxf(mx, __shfl_xor(mx, 4));
        mx = fmaxf(mx, __shfl_xor(mx, 8));
        const float mnew = fmaxf(mrun[mi][j], mx);
        const float corr = __builtin_amdgcn_exp2f((mrun[mi][j] - mnew) * LOG2E);
        mrun[mi][j] = mnew;
        const float p0 = __builtin_amdgcn_exp2f((s0 - mnew) * LOG2E);
        const float p1 = __builtin_amdgcn_exp2f((s1 - mnew) * LOG2E);
        const float p2 = __builtin_amdgcn_exp2f((s2 - mnew) * LOG2E);
        const float p3 = __builtin_amdgcn_exp2f((s3 - mnew) * LOG2E);
        float ps = p0 + p1 + p2 + p3;
        ps += __shfl_xor(ps, 1);
        ps += __shfl_xor(ps, 2);
        ps += __shfl_xor(ps, 4);
        ps += __shfl_xor(ps, 8);
        lrun[mi][j] = lrun[mi][j] * corr + ps;
        #pragma unroll
        for (int ni = 0; ni < 4; ++ni) accO[mi][ni][j] *= corr;
        const int pr = mi * 16 + lj + j;
        Ps[w][pr][0 * 16 + lr] = f2bf(p0);
        Ps[w][pr][1 * 16 + lr] = f2bf(p1);
        Ps[w][pr][2 * 16 + lr] = f2bf(p2);
        Ps[w][pr][3 * 16 + lr] = f2bf(p3);
      }
    }

    // intra-wave LDS RAW fence for Ps (rule #18: waitcnt + sched_barrier)
    asm volatile("s_waitcnt lgkmcnt(0)" ::: "memory");
    __builtin_amdgcn_sched_barrier(0);

    // O += P V   (B^T operand = V^T rows, kpos-contiguous)
    #pragma unroll
    for (int kk = 0; kk < 2; ++kk) {
      bf16x8 bv[4];
      #pragma unroll
      for (int ni = 0; ni < 4; ++ni)
        bv[ni] = *(const bf16x8*)&Vs[ni * 16 + lr][kk * 32 + lk];
      #pragma unroll
      for (int mi = 0; mi < 2; ++mi) {
        bf16x8 pa = *(const bf16x8*)&Ps[w][mi * 16 + lr][kk * 32 + lk];
        #pragma unroll
        for (int ni = 0; ni < 4; ++ni)
          accO[mi][ni] = __builtin_amdgcn_mfma_f32_16x16x32_bf16(pa, bv[ni], accO[mi][ni], 0, 0, 0);
      }
    }
    __syncthreads();
  }

  const int b = bh >> 3, h = bh & 7;
  #pragma unroll
  for (int mi = 0; mi < 2; ++mi) {
    #pragma unroll
    for (int j = 0; j < 4; ++j) {
      const float inv = 1.0f / lrun[mi][j];
      const int s = q0 + mi * 16 + lj + j;
      #pragma unroll
      for (int ni = 0; ni < 4; ++ni) {
        const int d = ni * 16 + lr;
        Cc[((size_t)(b * 2048 + s)) * 512 + h * 64 + d] = f2bf(accO[mi][ni][j] * inv);
      }
    }
  }
}

extern "C" void kernel_launch(void* const* d_in, const int* in_sizes, int n_in,
                              void* d_out, int out_size, void* d_ws, size_t ws_size,
                              hipStream_t stream)
{
  const float* q  = (const float*)d_in[0];
  const float* k  = (const float*)d_in[1];
  const float* v  = (const float*)d_in[2];
  const float* Wq = (const float*)d_in[3];
  const float* bq = (const float*)d_in[4];
  const float* Wk = (const float*)d_in[5];
  const float* bk = (const float*)d_in[6];
  const float* Wv = (const float*)d_in[7];
  const float* bv = (const float*)d_in[8];
  const float* Wo = (const float*)d_in[9];
  const float* bo = (const float*)d_in[10];
  float* out = (float*)d_out;

  char* ws = (char*)d_ws;
  short* WqT = (short*)(ws + 0 * 524288);
  short* WkT = (short*)(ws + 1 * 524288);
  short* WvT = (short*)(ws + 2 * 524288);
  short* WoT = (short*)(ws + 3 * 524288);
  short* Qh  = (short*)(ws + 4 * 524288);
  short* Kh  = (short*)(ws + 4 * 524288 + 1 * 8388608);
  short* VhT = (short*)(ws + 4 * 524288 + 2 * 8388608);
  short* Cc  = (short*)(ws + 4 * 524288 + 3 * 8388608);

  wtrans<<<dim3(16, 16, 4), 256, 0, stream>>>(Wq, Wk, Wv, Wo, WqT, WkT, WvT, WoT);
  gemm512<true,  false, 0><<<dim3(64, 4), 256, 0, stream>>>(q, WqT, bq, Qh);
  gemm512<true,  false, 0><<<dim3(64, 4), 256, 0, stream>>>(k, WkT, bk, Kh);
  gemm512<false, true,  1><<<dim3(4, 64), 256, 0, stream>>>(WvT, v, bv, VhT);
  attn<<<dim3(16, 32), 256, 0, stream>>>(Qh, Kh, VhT, Cc);
  gemm512<false, false, 2><<<dim3(64, 4), 256, 0, stream>>>(Cc, WoT, bo, out);
}